// Round 4
// baseline (21386.835 us; speedup 1.0000x reference)
//
#include <hip/hip_runtime.h>

typedef __attribute__((ext_vector_type(4))) float f4;
typedef __attribute__((ext_vector_type(8))) short frag8;
typedef unsigned long long u64;
typedef unsigned int u32;
typedef unsigned short u16;

#define ALPHA 0.3f

// ---- ws layout (bytes) ----
#define WHH_OFF   0ull                 // 3072*1024 bf16 = 6291456
#define WIH_OFF   6291456ull           // 3072*128 bf16  = 786432
#define HBUF_OFF  7077888ull           // 2 parities * 8 groups * 64KB = 1048576
#define FLG_OFF   8126464ull           // 8 groups * 32 WGs * 4 waves * u32 = 4096
#define ST1_OFF   8130560ull           // 256*2 fp32
#define ZERO_LEN  1052672ull           // hbuf + flags

__device__ __forceinline__ u16 f2bf(float f) {
  u32 u = __float_as_uint(f);
  u32 r = (u + 0x7FFFu + ((u >> 16) & 1u)) >> 16;
  return (u16)r;
}
__device__ __forceinline__ float bf2f(u16 h) {
  return __uint_as_float(((u32)h) << 16);
}
__device__ __forceinline__ float sigmf(float x) {
  float e = __expf(-fabsf(x));
  float s = 1.0f / (1.0f + e);
  return x >= 0.f ? s : 1.0f - s;
}
__device__ __forceinline__ float tanhf_(float x) {
  float e = __expf(-2.0f * fabsf(x));
  float t = (1.0f - e) / (1.0f + e);
  return x >= 0.f ? t : -t;
}
__device__ __forceinline__ frag8 pack_bf16(f4 a, f4 b) {
  union { u16 h[8]; frag8 f; } u;
  u.h[0] = f2bf(a[0]); u.h[1] = f2bf(a[1]); u.h[2] = f2bf(a[2]); u.h[3] = f2bf(a[3]);
  u.h[4] = f2bf(b[0]); u.h[5] = f2bf(b[1]); u.h[6] = f2bf(b[2]); u.h[7] = f2bf(b[3]);
  return u.f;
}

// fp32 -> bf16 weight conversion (W_hh then W_ih), exact-sized grid.
__global__ void prep_bf16(const float* __restrict__ whh_f32,
                          const float* __restrict__ wih_f32,
                          u16* __restrict__ whh, u16* __restrict__ wih) {
  int i = blockIdx.x * 256 + threadIdx.x;
  const int nhh = 3072 * 1024;
  if (i < nhh) whh[i] = f2bf(whh_f32[i]);
  else         wih[i - nhh] = f2bf(wih_f32[i - nhh]);
}

// Persistent GRU. 256 WGs = 8 groups (batch slices of 32) x 32 WGs (32 H-cols).
// h exchanged UNTAGGED in natural [b][col] bf16 layout (64 KB/group, read
// exactly once per WG per step). Readiness via per-producer-WAVE flaglets:
// producer wave release-stores flags[g][w][v]=t+1 after its h stores; consumer
// wave polls the 32 flaglets of its 8 producers with one coalesced 128B load
// (retry traffic = 128 B/wave, vs 4 KB/wave data-polling in R3).
// Write-after-read safety: WG stores h_{t+1} only after ALL 32 producer WGs
// signaled t (each of its 4 waves gates 8 producers; __syncthreads unions
// them), and flag=t transitively implies that WG finished reading h_{t-1}.
__global__ __launch_bounds__(256, 1) void gru_kernel(
    const float* __restrict__ x,       // [256][1024][128]
    const float* __restrict__ b_ih,    // [3072]
    const float* __restrict__ b_hh,    // [3072]
    const u16* __restrict__ whh,       // [3072][1024] bf16
    const u16* __restrict__ wih,       // [3072][128] bf16
    u16* __restrict__ hbuf,            // [2][8][32][1024] bf16
    u32* __restrict__ flags,           // [8][32][4]
    float* __restrict__ st1)           // [256][2]
{
  __shared__ f4 xbuf[4096];            // 64 KB K-partials (single buffer, 2 syncs)
  __shared__ u16 sbuf[1024];           // 2 KB h staging (u16 -> u32 repack)
  const int wg = blockIdx.x;
  const int g = wg >> 5, w = wg & 31;
  const int tid = threadIdx.x;
  const int v = tid >> 6;              // wave = K-slice of 256
  const int l = tid & 63;
  const int lm = l & 15, lq = l >> 4;

  // ---- persistent weight fragments ----
  // B-frag 16x16x32: n = lane&15 -> gate row, k = (lane>>4)*8 + j
  frag8 whhf[8][6];
  frag8 wihf[6];
#pragma unroll
  for (int rt = 0; rt < 6; ++rt) {
    int grow = (rt >> 1) * 1024 + w * 32 + (rt & 1) * 16 + lm;
    wihf[rt] = *(const frag8*)(wih + grow * 128 + v * 32 + lq * 8);
#pragma unroll
    for (int kb = 0; kb < 8; ++kb)
      whhf[kb][rt] = *(const frag8*)(whh + grow * 1024 + v * 256 + kb * 32 + lq * 8);
  }

  // ---- update-phase constants: thread <-> (4 batches ub0.., col uc) ----
  const int uc = tid & 31;
  const int ub0 = (tid >> 5) << 2;
  const int colg = w * 32 + uc;
  const float bir = b_ih[colg],         bhr = b_hh[colg];
  const float biz = b_ih[1024 + colg],  bhz = b_hh[1024 + colg];
  const float bin_ = b_ih[2048 + colg], bhn = b_hh[2048 + colg];
  f4 hprev = {0.f, 0.f, 0.f, 0.f};

  // ---- EMA state in A-frag order; x prefetched one step ahead ----
  f4 e0a, e0b, e1a, e1b;
  const float* xb0 = x + (size_t)(g * 32 + lm) * 131072 + v * 32 + lq * 8;
  const float* xb1 = x + (size_t)(g * 32 + 16 + lm) * 131072 + v * 32 + lq * 8;
  f4 xn0 = *(const f4*)xb0, xn1 = *(const f4*)(xb0 + 4);
  f4 xn2 = *(const f4*)xb1, xn3 = *(const f4*)(xb1 + 4);

  u32* flg = flags + g * 128;          // [w][v] flaglets for this group
  const u32 fidx = v * 32 + (l & 31);  // this wave's 8 producers x 4 waves
  const float A1 = 1.0f - ALPHA;
  const f4 zz = {0.f, 0.f, 0.f, 0.f};
  f4 acc[2][6], accn[2][2];

#pragma unroll 1
  for (int t = 0; t < 1024; ++t) {
    const u64* hr64 = (const u64*)(hbuf + (size_t)((t & 1) * 8 + g) * 32768);
    u32* hw32 = (u32*)(hbuf + (size_t)(((t + 1) & 1) * 8 + g) * 32768);

    // ---- A: all h-independent work first (gives producers time) ----
    if (t == 0) { e0a = xn0; e0b = xn1; e1a = xn2; e1b = xn3; }
    else {
      e0a = A1 * xn0 + ALPHA * e0a; e0b = A1 * xn1 + ALPHA * e0b;
      e1a = A1 * xn2 + ALPHA * e1a; e1b = A1 * xn3 + ALPHA * e1b;
    }
    frag8 smf0 = pack_bf16(e0a, e0b);
    frag8 smf1 = pack_bf16(e1a, e1b);
    {
      size_t to = (size_t)(t < 1023 ? t + 1 : 1023) * 128;
      xn0 = *(const f4*)(xb0 + to); xn1 = *(const f4*)(xb0 + to + 4);
      xn2 = *(const f4*)(xb1 + to); xn3 = *(const f4*)(xb1 + to + 4);
    }
#pragma unroll
    for (int bh = 0; bh < 2; ++bh) {
#pragma unroll
      for (int rt = 0; rt < 6; ++rt) acc[bh][rt] = zz;
      accn[bh][0] = zz; accn[bh][1] = zz;
    }
#pragma unroll
    for (int rt = 0; rt < 4; ++rt) {
      acc[0][rt] = __builtin_amdgcn_mfma_f32_16x16x32_bf16(smf0, wihf[rt], acc[0][rt], 0, 0, 0);
      acc[1][rt] = __builtin_amdgcn_mfma_f32_16x16x32_bf16(smf1, wihf[rt], acc[1][rt], 0, 0, 0);
    }
#pragma unroll
    for (int nt = 0; nt < 2; ++nt) {
      accn[0][nt] = __builtin_amdgcn_mfma_f32_16x16x32_bf16(smf0, wihf[4 + nt], accn[0][nt], 0, 0, 0);
      accn[1][nt] = __builtin_amdgcn_mfma_f32_16x16x32_bf16(smf1, wihf[4 + nt], accn[1][nt], 0, 0, 0);
    }

    // ---- B: gate on this wave's 8 producers (coalesced 128B flag load) ----
    {
      const u32 tgt = (u32)t;
      for (;;) {
        u32 f = __hip_atomic_load(flg + fidx, __ATOMIC_RELAXED, __HIP_MEMORY_SCOPE_AGENT);
        if (__ballot(f < tgt) == 0ull) break;
        __builtin_amdgcn_s_sleep(2);
      }
      asm volatile("" ::: "memory");   // compiler fence; LLC ordering does the rest
    }

    // ---- C: h loads (read-once, untagged) + 96 gh MFMAs ----
    frag8 af[8][2];
#pragma unroll
    for (int kb = 0; kb < 8; ++kb) {
#pragma unroll
      for (int bh = 0; bh < 2; ++bh) {
        const u64* p = hr64 + (bh * 16 + lm) * 256 + (v * 8 + kb) * 8 + lq * 2;
        union { u64 q[2]; frag8 f; } uu;
        uu.q[0] = __hip_atomic_load(p,     __ATOMIC_RELAXED, __HIP_MEMORY_SCOPE_AGENT);
        uu.q[1] = __hip_atomic_load(p + 1, __ATOMIC_RELAXED, __HIP_MEMORY_SCOPE_AGENT);
        af[kb][bh] = uu.f;
      }
    }
#pragma unroll
    for (int kb = 0; kb < 8; ++kb) {
#pragma unroll
      for (int rt = 0; rt < 6; ++rt) {
        acc[0][rt] = __builtin_amdgcn_mfma_f32_16x16x32_bf16(af[kb][0], whhf[kb][rt], acc[0][rt], 0, 0, 0);
        acc[1][rt] = __builtin_amdgcn_mfma_f32_16x16x32_bf16(af[kb][1], whhf[kb][rt], acc[1][rt], 0, 0, 0);
      }
    }

    // ---- D: K-partials to LDS (XOR-swizzled b128), reduce, gates ----
#pragma unroll
    for (int bh = 0; bh < 2; ++bh) {
      int b8 = bh * 4 + lq;
#pragma unroll
      for (int rt = 0; rt < 6; ++rt) {
        int gr = rt * 16 + lm;
        xbuf[((v * 128 + gr) << 3) | (b8 ^ (gr & 7))] = acc[bh][rt];
      }
#pragma unroll
      for (int nt = 0; nt < 2; ++nt) {
        int gr = 96 + nt * 16 + lm;
        xbuf[((v * 128 + gr) << 3) | (b8 ^ (gr & 7))] = accn[bh][nt];
      }
    }
    __syncthreads();   // (A) partials visible

    int swz = (ub0 >> 2) ^ (uc & 7);
    f4 sr = zz, sz4 = zz, gn4 = zz, gin4 = zz;
#pragma unroll
    for (int vv = 0; vv < 4; ++vv) {
      sr   += xbuf[((vv * 128 + uc) << 3) | swz];
      sz4  += xbuf[((vv * 128 + 32 + uc) << 3) | swz];
      gn4  += xbuf[((vv * 128 + 64 + uc) << 3) | swz];
      gin4 += xbuf[((vv * 128 + 96 + uc) << 3) | swz];
    }
    f4 h4;
#pragma unroll
    for (int i = 0; i < 4; ++i) {
      float rr = sigmf(sr[i] + bir + bhr);
      float zg = sigmf(sz4[i] + biz + bhz);
      float nn = tanhf_(gin4[i] + bin_ + rr * (gn4[i] + bhn));
      h4[i] = (1.0f - zg) * nn + zg * hprev[i];
    }
    hprev = h4;
#pragma unroll
    for (int i = 0; i < 4; ++i) sbuf[(ub0 + i) * 32 + uc] = f2bf(h4[i]);
    __syncthreads();   // (B) staging complete (also fences xbuf reads)

    // ---- E: coalesced u32 h stores + per-wave release flaglet ----
    {
      const u32* s32 = (const u32*)sbuf;
      u32 a0 = s32[tid], a1 = s32[tid + 256];
      int b0 = tid >> 4,        c0 = tid & 15;
      int b1 = (tid + 256) >> 4, c1 = tid & 15;
      __hip_atomic_store(hw32 + b0 * 512 + w * 16 + c0, a0, __ATOMIC_RELAXED, __HIP_MEMORY_SCOPE_AGENT);
      __hip_atomic_store(hw32 + b1 * 512 + w * 16 + c1, a1, __ATOMIC_RELAXED, __HIP_MEMORY_SCOPE_AGENT);
      if (l == 0)
        __hip_atomic_store(flg + w * 4 + v, (u32)(t + 1), __ATOMIC_RELEASE, __HIP_MEMORY_SCOPE_AGENT);
    }
  }

  // st_1 columns 1,2 (fp32) for denorm; EMA regs hold state at t=1023
  if (w == 0 && v == 0 && lq == 0) {
    st1[(g * 32 + lm) * 2 + 0] = e0a[1];
    st1[(g * 32 + lm) * 2 + 1] = e0a[2];
    st1[(g * 32 + 16 + lm) * 2 + 0] = e1a[1];
    st1[(g * 32 + 16 + lm) * 2 + 1] = e1a[2];
  }
}

// out[b][o] = (h_T[b] . W_fc[o] + b_fc[o] - a*st1[b][o]) / (1-a)
__global__ void fc_kernel(const u16* __restrict__ hbuf,   // parity-0: [8][32][1024]
                          const float* __restrict__ wfc,  // [2][1024]
                          const float* __restrict__ bfc,  // [2]
                          const float* __restrict__ st1,  // [256][2]
                          float* __restrict__ out)        // [256][2]
{
  int b = blockIdx.x, t = threadIdx.x;
  int g = b >> 5, bl = b & 31;
  int k0 = t * 4;
  u64 hv = ((const u64*)(hbuf + (size_t)g * 32768))[bl * 256 + t];
  float h0 = bf2f((u16)(hv & 0xFFFF)),         h1 = bf2f((u16)((hv >> 16) & 0xFFFF));
  float h2 = bf2f((u16)((hv >> 32) & 0xFFFF)), h3 = bf2f((u16)(hv >> 48));
  float s0 = h0 * wfc[k0] + h1 * wfc[k0 + 1] + h2 * wfc[k0 + 2] + h3 * wfc[k0 + 3];
  float s1 = h0 * wfc[1024 + k0] + h1 * wfc[1024 + k0 + 1] +
             h2 * wfc[1024 + k0 + 2] + h3 * wfc[1024 + k0 + 3];
#pragma unroll
  for (int off = 32; off > 0; off >>= 1) {
    s0 += __shfl_down(s0, off);
    s1 += __shfl_down(s1, off);
  }
  __shared__ float red[8];
  if ((t & 63) == 0) { red[(t >> 6) * 2] = s0; red[(t >> 6) * 2 + 1] = s1; }
  __syncthreads();
  if (t == 0) {
    float a0 = red[0] + red[2] + red[4] + red[6] + bfc[0];
    float a1 = red[1] + red[3] + red[5] + red[7] + bfc[1];
    float inv = 1.0f / (1.0f - ALPHA);
    out[b * 2 + 0] = (a0 - ALPHA * st1[b * 2 + 0]) * inv;
    out[b * 2 + 1] = (a1 - ALPHA * st1[b * 2 + 1]) * inv;
  }
}

extern "C" void kernel_launch(void* const* d_in, const int* in_sizes, int n_in,
                              void* d_out, int out_size, void* d_ws, size_t ws_size,
                              hipStream_t stream) {
  const float* x   = (const float*)d_in[0];
  const float* Wih = (const float*)d_in[1];
  const float* Whh = (const float*)d_in[2];
  const float* bih = (const float*)d_in[3];
  const float* bhh = (const float*)d_in[4];
  const float* Wfc = (const float*)d_in[5];
  const float* bfc = (const float*)d_in[6];
  char* ws = (char*)d_ws;
  u16* whh_bf = (u16*)(ws + WHH_OFF);
  u16* wih_bf = (u16*)(ws + WIH_OFF);
  u16* hbuf   = (u16*)(ws + HBUF_OFF);
  u32* flags  = (u32*)(ws + FLG_OFF);
  float* st1  = (float*)(ws + ST1_OFF);

  hipMemsetAsync(ws + HBUF_OFF, 0, ZERO_LEN, stream);   // h0 = 0, flags = 0
  prep_bf16<<<13824, 256, 0, stream>>>(Whh, Wih, whh_bf, wih_bf);
  gru_kernel<<<256, 256, 0, stream>>>(x, bih, bhh, whh_bf, wih_bf, hbuf, flags, st1);
  fc_kernel<<<256, 256, 0, stream>>>(hbuf, Wfc, bfc, st1, (float*)d_out);
}